// Round 6
// baseline (147.133 us; speedup 1.0000x reference)
//
#include <hip/hip_runtime.h>
#include <stdint.h>

typedef unsigned short ushort_t;
typedef __bf16 bf16x8 __attribute__((ext_vector_type(8)));
typedef __bf16 bf16x2 __attribute__((ext_vector_type(2)));
typedef float f32x4 __attribute__((ext_vector_type(4)));
typedef float f32x16 __attribute__((ext_vector_type(16)));

#define T_SEQ 4096
#define D_MODEL 896
#define CHUNKS_PER_BLOCK 4   // target chunks per attention block (balance quantum)
#define MAXSPLIT 8           // max splits per tile (t=63 -> 8)

// Attention LDS strides (u16 units, 8-multiples for ds_read_b128 alignment).
#define LSK 136   // 68 dwords/row
#define LSV 72    // 36 dwords/row; lane=key scatter spans all 32 banks

// Fano lines, residues sorted ascending per head
__constant__ int d_LINEMASK[7] = {0x07, 0x19, 0x61, 0x2A, 0x52, 0x4C, 0x34};
__constant__ int d_R[7][3] = {{0,1,2},{0,3,4},{0,5,6},{1,3,5},{1,4,6},{2,3,6},{2,4,5}};

__device__ inline unsigned f2bf(float f) {
    unsigned x = __float_as_uint(f);
    return (x + 0x7fffu + ((x >> 16) & 1u)) >> 16;   // RNE
}
__device__ inline float lo_f(unsigned x) { return __uint_as_float(x << 16); }
__device__ inline float hi_f(unsigned x) { return __uint_as_float(x & 0xFFFF0000u); }

// pack two f32 -> u32 of 2 bf16 via HW cvt (RNE; compiler emits v_cvt_pk_bf16_f32)
__device__ __forceinline__ unsigned pk_bf2(float lo, float hi) {
    union { bf16x2 h; unsigned u; } cv;
    cv.h = (bf16x2){(__bf16)lo, (__bf16)hi};
    return cv.u;
}

// ---------------------------------------------------------------------------
// Static balanced schedule (R11). Head-independent upper bound on the chunk
// count of tile t; split count S(t) = ceil(ntot_ub/CHUNKS_PER_BLOCK) so every
// attention block runs <= 4 chunks. Same formula on host (grid size) and
// device (tile lookup); all wave-uniform SALU.
// ---------------------------------------------------------------------------
__host__ __device__ inline int nsplit_of(int t) {
    int a = (192 * t + 189) / 7 + 3;        // >= any head's ncomp for this tile
    int nch_ub = (a + 63) >> 6;             // >= any head's nch
    return (nch_ub + 2 + CHUNKS_PER_BLOCK - 1) / CHUNKS_PER_BLOCK;  // ntot_ub/4
}

// ---------------------------------------------------------------------------
// fp32 -> bf16 bulk convert, 5 tensors (x, Wq, Wk, Wv, Wo). 8 elem/thread.
// ---------------------------------------------------------------------------
__global__ __launch_bounds__(256)
void cvt5(const float* __restrict__ x,  const float* __restrict__ wq,
          const float* __restrict__ wk, const float* __restrict__ wv,
          const float* __restrict__ wo,
          ushort_t* __restrict__ xb,  ushort_t* __restrict__ wqb,
          ushort_t* __restrict__ wkb, ushort_t* __restrict__ wvb,
          ushort_t* __restrict__ wob) {
    const int ten = blockIdx.y;
    const float* s = (ten == 0) ? x : (ten == 1) ? wq : (ten == 2) ? wk
                   : (ten == 3) ? wv : wo;
    ushort_t* d = (ten == 0) ? xb : (ten == 1) ? wqb : (ten == 2) ? wkb
                : (ten == 3) ? wvb : wob;
    const int n8 = ((ten == 0) ? T_SEQ * D_MODEL : D_MODEL * D_MODEL) >> 3;
    for (int i = blockIdx.x * 256 + threadIdx.x; i < n8; i += gridDim.x * 256) {
        float4 a = ((const float4*)s)[2 * i];
        float4 b = ((const float4*)s)[2 * i + 1];
        uint4 u;
        u.x = f2bf(a.x) | (f2bf(a.y) << 16);
        u.y = f2bf(a.z) | (f2bf(a.w) << 16);
        u.z = f2bf(b.x) | (f2bf(b.y) << 16);
        u.w = f2bf(b.z) | (f2bf(b.w) << 16);
        ((uint4*)d)[i] = u;
    }
}

// async global->LDS DMA, 16 B/lane. LDS dest = wave-uniform base + lane*16.
__device__ __forceinline__ void async_cp16(const void* g, void* l) {
    __builtin_amdgcn_global_load_lds(
        (__attribute__((address_space(1))) void*)g,
        (__attribute__((address_space(3))) void*)l,
        16, 0, 0);
}

// ---------------------------------------------------------------------------
// C[M,N] = A[M,K] @ B[N,K]^T, bf16 in, fp32 acc, bf16/fp32 out (R9-verified).
// m97 structure: 128x128 tile, BK=32, DMA staging. z selects (B,C) pair.
// ---------------------------------------------------------------------------
template <bool C32>
__global__ __launch_bounds__(256)
void gemm_nt_dma(const ushort_t* __restrict__ A,
                 const ushort_t* __restrict__ B0,
                 const ushort_t* __restrict__ B1,
                 const ushort_t* __restrict__ B2,
                 void* __restrict__ C0,
                 void* __restrict__ C1,
                 void* __restrict__ C2) {
    const int z = blockIdx.z;
    const ushort_t* B = (z == 0) ? B0 : (z == 1) ? B1 : B2;
    void* C = (z == 0) ? C0 : (z == 1) ? C1 : C2;

    const int K = D_MODEL, N = D_MODEL;
    const int i0 = blockIdx.x * 128;
    const int n0 = blockIdx.y * 128;

    __shared__ __align__(16) ushort_t As[128 * 32];   // NO padding (DMA layout)
    __shared__ __align__(16) ushort_t Bs[128 * 32];

    const int t = threadIdx.x;
    const int w = t >> 6, lane = t & 63;
    const int wm = (w >> 1) * 64, wn = (w & 1) * 64;
    const int lr = lane & 15, lq = lane >> 4;

    const int srow = w * 16 + (lane >> 2);
    const int scol = (lane & 3) * 8;
    const ushort_t* gA0 = A + (size_t)(i0 + srow) * K + scol;
    const ushort_t* gA1 = A + (size_t)(i0 + 64 + srow) * K + scol;
    const ushort_t* gB0 = B + (size_t)(n0 + srow) * K + scol;
    const ushort_t* gB1 = B + (size_t)(n0 + 64 + srow) * K + scol;
    ushort_t* lA0 = &As[(w * 16) * 32];
    ushort_t* lA1 = &As[(64 + w * 16) * 32];
    ushort_t* lB0 = &Bs[(w * 16) * 32];
    ushort_t* lB1 = &Bs[(64 + w * 16) * 32];

    f32x4 acc[4][4];
#pragma unroll
    for (int a = 0; a < 4; a++)
#pragma unroll
        for (int b = 0; b < 4; b++) acc[a][b] = (f32x4){0.f, 0.f, 0.f, 0.f};

    for (int k0 = 0; k0 < K; k0 += 32) {
        __syncthreads();
        async_cp16(gA0 + k0, lA0);
        async_cp16(gA1 + k0, lA1);
        async_cp16(gB0 + k0, lB0);
        async_cp16(gB1 + k0, lB1);
        __builtin_amdgcn_s_waitcnt(0);
        __syncthreads();

        bf16x8 af[4], bfr[4];
#pragma unroll
        for (int mi = 0; mi < 4; mi++)
            af[mi] = *(const bf16x8*)&As[(wm + mi * 16 + lr) * 32 + lq * 8];
#pragma unroll
        for (int ni = 0; ni < 4; ni++)
            bfr[ni] = *(const bf16x8*)&Bs[(wn + ni * 16 + lr) * 32 + lq * 8];
#pragma unroll
        for (int mi = 0; mi < 4; mi++)
#pragma unroll
            for (int ni = 0; ni < 4; ni++)
                acc[mi][ni] = __builtin_amdgcn_mfma_f32_16x16x32_bf16(
                    af[mi], bfr[ni], acc[mi][ni], 0, 0, 0);
    }

    // C/D layout: col = lane&15, row = (lane>>4)*4 + reg
    if (C32) {
        float* Cf = (float*)C;
#pragma unroll
        for (int mi = 0; mi < 4; mi++)
#pragma unroll
            for (int ni = 0; ni < 4; ni++)
#pragma unroll
                for (int r = 0; r < 4; r++) {
                    int row = i0 + wm + mi * 16 + lq * 4 + r;
                    int col = n0 + wn + ni * 16 + lr;
                    Cf[(size_t)row * N + col] = acc[mi][ni][r];
                }
    } else {
        ushort_t* Cb = (ushort_t*)C;
#pragma unroll
        for (int mi = 0; mi < 4; mi++)
#pragma unroll
            for (int ni = 0; ni < 4; ni++)
#pragma unroll
                for (int r = 0; r < 4; r++) {
                    int row = i0 + wm + mi * 16 + lq * 4 + r;
                    int col = n0 + wn + ni * 16 + lr;
                    Cb[(size_t)row * N + col] = (ushort_t)f2bf(acc[mi][ni][r]);
                }
    }
}

// scatter 8 dims of one key's V into Vt[d][key] (stride LSV); lane=key mapping
__device__ inline void vt_scatter8(ushort_t* vtcol, uint4 vv) {
    vtcol[0 * LSV] = (ushort_t)(vv.x & 0xFFFFu);
    vtcol[1 * LSV] = (ushort_t)(vv.x >> 16);
    vtcol[2 * LSV] = (ushort_t)(vv.y & 0xFFFFu);
    vtcol[3 * LSV] = (ushort_t)(vv.y >> 16);
    vtcol[4 * LSV] = (ushort_t)(vv.z & 0xFFFFu);
    vtcol[5 * LSV] = (ushort_t)(vv.z >> 16);
    vtcol[6 * LSV] = (ushort_t)(vv.w & 0xFFFFu);
    vtcol[7 * LSV] = (ushort_t)(vv.w >> 16);
}

// compacted-index -> key: p -> j = 7*(p/3) + r[p%3]
__device__ inline int jof(int p, int r0, int r1, int r2) {
    int g = p / 3, rs = p - 3 * g;
    return 7 * g + ((rs == 0) ? r0 : (rs == 1) ? r1 : r2);
}

// issue chunk's K/V global loads for this lane into registers (no LDS write).
// OOR j -> zeros. 32 VGPR held; latency hidden under the previous chunk's
// compute (T14 async-STAGE split: issue-early / write-late).
__device__ __forceinline__ void issue_kv(const ushort_t* __restrict__ Kb,
                                         const ushort_t* __restrict__ Vb,
                                         int j, int h, int dim0,
                                         uint4 kreg[4], uint4 vreg[4]) {
    if (j >= 0 && j < T_SEQ) {
        const ushort_t* kp = Kb + (size_t)j * D_MODEL + h * 128 + dim0;
        const ushort_t* vp = Vb + (size_t)j * D_MODEL + h * 128 + dim0;
#pragma unroll
        for (int v = 0; v < 4; v++) {
            kreg[v] = *(const uint4*)(kp + v * 8);
            vreg[v] = *(const uint4*)(vp + v * 8);
        }
    } else {
        uint4 zz = {0u, 0u, 0u, 0u};
#pragma unroll
        for (int v = 0; v < 4; v++) { kreg[v] = zz; vreg[v] = zz; }
    }
}

// write the prefetched registers into Ks (row-major) / Vt (transposed).
__device__ __forceinline__ void write_kv(ushort_t* Ks, ushort_t* Vt,
                                         int kk, int dim0,
                                         const uint4 kreg[4], const uint4 vreg[4]) {
#pragma unroll
    for (int v = 0; v < 4; v++) {
        *(uint4*)&Ks[kk * LSK + dim0 + v * 8] = kreg[v];
        vt_scatter8(&Vt[(dim0 + v * 8) * LSV + kk], vreg[v]);
    }
}

// ---------------------------------------------------------------------------
// Balanced split-K MFMA Fano attention (R15: 32x32 MFMA, dbuf LDS).
// Grid (NP, 7), NP = sum_t nsplit_of(t); every block runs <= 4 chunks.
//
// R15 structure (DS-pipe was the hidden bottleneck: ~160 KB LDS moved per
// chunk per block, 4x K/V read duplication because every 16-row wave spanned
// all 64 keys):
//  * mfma_f32_32x32x16_bf16, wave = 32 q-rows x 32 keys. 4 waves = 2 wq x 2
//    wk. K/V LDS reads per chunk per block: 128 KB -> 64 KB.
//  * swapped BOTH products: S^T = mfma(A=K, B=Q) and O^T = mfma(A=V^T, B=P^T).
//    C/D layout (col = lane&31, row = (reg&3)+8*(reg>>2)+4*(lane>>5)) puts
//    BOTH S and O columns at q = lane&31: softmax reduce = 15 in-lane +
//    1 shfl_xor(32); O-rescale is lane-local (0 shuffles); P->B-frag needs
//    only 4 bpermutes/wave (was 24).
//  * LDS double-buffer, ONE __syncthreads per chunk (write nxt || compute
//    cur). LDS 2x35840 = 71680 B -> 2 blocks/CU; VGPR ~175 -> (256,2).
//  * wk halves merged in-LDS once per block (Ks reused as scratch) ->
//    Opart/Lm format and merge kernel unchanged.
// Retained: balanced schedule, reg-prefetch, defer-max, interior fast-path.
// ---------------------------------------------------------------------------
__global__ __launch_bounds__(256, 2)
void fano_attn_split(const ushort_t* __restrict__ Qb,
                     const ushort_t* __restrict__ Kb,
                     const ushort_t* __restrict__ Vb,
                     ushort_t* __restrict__ Opart,
                     float* __restrict__ Lm) {
    const int h = blockIdx.y;
    const int p = (int)gridDim.x - 1 - (int)blockIdx.x;  // LPT: big tiles first

    // tile lookup: find t with P[t] <= p < P[t]+S(t)  (wave-uniform)
    int tile = 63, pbase0 = 0;
    for (int u = 0; u < 64; ++u) {
        int s = nsplit_of(u);
        if (p < pbase0 + s) { tile = u; break; }
        pbase0 += s;
    }
    const int sp = p - pbase0;            // split index within tile
    const int Sloc = nsplit_of(tile);

    const int i0 = tile * 64;
    const int t = threadIdx.x;
    const int w = t >> 6, lane = t & 63;
    const int wq = w >> 1, wk = w & 1;    // wave = q-rows [wq*32,+32) x keys [wk*32,+32)
    const int q = lane & 31;              // local q-row (S/O column)
    const int hl = lane >> 5;             // half-lane group
    const int iq = i0 + wq * 32 + q;      // this lane's q-row

    __shared__ __align__(16) ushort_t Ks[2][64 * LSK];   // 2 x 17408 B
    __shared__ __align__(16) ushort_t Vt[2][128 * LSV];  // 2 x 18432 B

    const int lm = d_LINEMASK[h];
    const int r0 = d_R[h][0], r1 = d_R[h][1], r2 = d_R[h][2];
    const float scale = 0.08838834764831845f;

    // Q B-frags: lane holds Q[iq][f*16 + hl*8 + (0..7)], f = 0..7
    bf16x8 qf[8];
    {
        const ushort_t* qrow = Qb + (size_t)iq * D_MODEL + h * 128;
#pragma unroll
        for (int f = 0; f < 8; f++)
            qf[f] = *(const bf16x8*)(qrow + f * 16 + hl * 8);
    }

    f32x16 O[4];
#pragma unroll
    for (int d4 = 0; d4 < 4; d4++)
#pragma unroll
        for (int e = 0; e < 16; e++) O[d4][e] = 0.f;
    float m = -1e30f;   // running max of q-row iq (key-half wk)
    float l = 0.f;      // running sum

    const int imax = i0 + 63;
    const int ncomp = (imax - r0) / 7 + (imax - r1) / 7 + (imax - r2) / 7 + 3;
    const int nch = (ncomp + 63) >> 6;
    const int ntot = nch + 2;                // + two linear band chunks
    const int cstart = (sp * ntot) / Sloc;   // this split's chunk sub-range
    const int cend = ((sp + 1) * ntot) / Sloc;

    // per-lane key index for chunk cc (staging gather; lane = key slot)
    auto chunk_j = [&](int cc) -> int {
        if (cc >= nch) {
            const int jbase = (cc == nch) ? i0 - 16 : i0 + 48;
            return jbase + lane;
        }
        return jof(cc * 64 + lane, r0, r1, r2);
    };

    // prologue: stage chunk cstart into buf0; issue cstart+1
    uint4 kreg[4], vreg[4];
    if (cstart < cend) {
        issue_kv(Kb, Vb, chunk_j(cstart), h, w * 32, kreg, vreg);
        write_kv(Ks[0], Vt[0], lane, w * 32, kreg, vreg);
        if (cstart + 1 < cend)
            issue_kv(Kb, Vb, chunk_j(cstart + 1), h, w * 32, kreg, vreg);
    }
    __syncthreads();
    int cur = 0;

    for (int cc = cstart; cc < cend; cc++) {
        const bool band = (cc >= nch);
        const int jbase = (cc == nch) ? i0 - 16 : i0 + 48;

        // (1) write NEXT chunk's prefetched regs into the other buffer
        //     (auto vmcnt waits; readers are on buf[cur] -> no barrier needed)
        if (cc + 1 < cend)
            write_kv(Ks[cur ^ 1], Vt[cur ^ 1], lane, w * 32, kreg, vreg);
        // (2) issue chunk cc+2's loads; in flight across the compute below
        if (cc + 2 < cend)
            issue_kv(Kb, Vb, chunk_j(cc + 2), h, w * 32, kreg, vreg);

        // wave-uniform skip: chunk min j beyond this wave's rows
        int jmin = band ? jbase : jof(cc * 64, r0, r1, r2);
        if (jmin <= i0 + wq * 32 + 31) {
            const ushort_t* KsC = Ks[cur];
            const ushort_t* VtC = Vt[cur];

            // S^T = K Q^T: A = K (m=key), B = Q (n=q). 8 k-windows of 16.
            f32x16 S;
#pragma unroll
            for (int e = 0; e < 16; e++) S[e] = 0.f;
#pragma unroll
            for (int f = 0; f < 8; f++) {
                bf16x8 kf = *(const bf16x8*)
                    &KsC[(wk * 32 + q) * LSK + f * 16 + hl * 8];
                S = __builtin_amdgcn_mfma_f32_32x32x16_bf16(kf, qf[f], S, 0, 0, 0);
            }

            // mask: S reg sr holds S[q=iq][key_local = (sr&3)+8*(sr>>2)+4*hl]
            const bool interior = !band && (jof(cc * 64 + 63, r0, r1, r2) <= i0 + wq * 32);
            if (interior) {
#pragma unroll
                for (int e = 0; e < 16; e++) S[e] *= scale;
            } else if (band) {
#pragma unroll
                for (int g4 = 0; g4 < 4; g4++) {
                    int j0 = jbase + wk * 32 + 8 * g4 + 4 * hl;
#pragma unroll
                    for (int e = 0; e < 4; e++) {
                        int j = j0 + e;
                        int jm = ((j % 7) + 7) % 7;
                        bool ok = (j >= 0) && !((lm >> jm) & 1) &&
                                  (j <= iq) && (j >= iq - 16);
                        S[g4 * 4 + e] = ok ? S[g4 * 4 + e] * scale : -1e30f;
                    }
                }
            } else {
                // straddling fano chunk: causal mask only
#pragma unroll
                for (int g4 = 0; g4 < 4; g4++) {
                    int p0 = cc * 64 + wk * 32 + 8 * g4 + 4 * hl;
                    int g = p0 / 3, rs = p0 - 3 * g;
#pragma unroll
                    for (int e = 0; e < 4; e++) {
                        int j = 7 * g + ((rs == 0) ? r0 : (rs == 1) ? r1 : r2);
                        S[g4 * 4 + e] = (j <= iq) ? S[g4 * 4 + e] * scale : -1e30f;
                        if (++rs == 3) { rs = 0; ++g; }
                    }
                }
            }

            // online softmax: row = q (lane-local 16 + partner via shfl_xor 32)
            float cm = -1e30f;
#pragma unroll
            for (int e = 0; e < 16; e++) cm = fmaxf(cm, S[e]);
            cm = fmaxf(cm, __shfl_xor(cm, 32));

            const bool defer = __all(cm <= m && m >= -60.f);
            float mn, a = 1.f;
            if (defer) {
                mn = m;
            } else {
                mn = fmaxf(fmaxf(m, cm), -60.f);   // all-masked -> exact 0
                a = __expf(m - mn);
                m = mn;
            }
            float rs_ = 0.f;
#pragma unroll
            for (int e = 0; e < 16; e++) {
                S[e] = __expf(S[e] - mn);          // S becomes P in place
                rs_ += S[e];
            }
            rs_ += __shfl_xor(rs_, 32);
            if (defer) {
                l = l + rs_;
            } else {
                l = l * a + rs_;
#pragma unroll
                for (int d4 = 0; d4 < 4; d4++)
#pragma unroll
                    for (int e = 0; e < 16; e++) O[d4][e] *= a;   // lane-local
            }

            // P^T B-frags per k-window f (16 keys). Frag elem e: key
            // f*16 + hl*8 + e; elems 0-3 sourced from hl0 lane, 4-7 from hl1,
            // both from source regs 8f+4*hl_target+{0..3}. Each lane sends its
            // regs 8f+4*(1-hl), keeps 8f+4*hl.
            bf16x8 pf[2];
#pragma unroll
            for (int f = 0; f < 2; f++) {
                unsigned lo0 = pk_bf2(S[8 * f + 0], S[8 * f + 1]);
                unsigned lo1 = pk_bf2(S[8 * f + 2], S[8 * f + 3]);
                unsigned hi0 = pk_bf2(S[8 * f + 4], S[8 * f + 5]);
                unsigned hi1 = pk_bf2(S[8 * f + 6], S[8 * f + 7]);
                unsigned s0 = hl ? lo0 : hi0;
                unsigned s1 = hl ? lo1 : hi1;
                unsigned rv0 = __shfl_xor(s0, 32);
                unsigned rv1 = __shfl_xor(s1, 32);
                uint4 tw;
                tw.x = hl ? rv0 : lo0;
                tw.y = hl ? rv1 : lo1;
                tw.z = hl ? hi0 : rv0;
                tw.w = hl ? hi1 : rv1;
                pf[f] = *(const bf16x8*)&tw;
            }

            // O^T += V^T P^T: A = V^T (m=d), B = P^T (n=q)
#pragma unroll
            for (int d4 = 0; d4 < 4; d4++) {
#pragma unroll
                for (int f = 0; f < 2; f++) {
                    bf16x8 vf = *(const bf16x8*)
                        &VtC[(d4 * 32 + q) * LSV + wk * 32 + f * 16 + hl * 8];
                    O[d4] = __builtin_amdgcn_mfma_f32_32x32x16_bf16(vf, pf[f], O[d4], 0, 0, 0);
                }
            }
        }

        __syncthreads();   // writes to nxt visible; reads of cur complete
        cur ^= 1;
    }

    // ---- in-LDS merge of the two wk key-halves (Opart/Lm format unchanged)
    float* sc = (float*)&Ks[0][0];     // 2 wq x 128 d x 32 q f32 = 32 KB
    float* mlsc = (float*)&Vt[0][0];   // 64 rows x {m,l}
    if (wk == 1) {
#pragma unroll
        for (int d4 = 0; d4 < 4; d4++)
#pragma unroll
            for (int e = 0; e < 16; e++) {
                int d = d4 * 32 + (e & 3) + 8 * (e >> 2) + 4 * hl;
                sc[((size_t)wq * 128 + d) * 32 + q] = O[d4][e];
            }
        if (hl == 0) {
            mlsc[(wq * 32 + q) * 2 + 0] = m;
            mlsc[(wq * 32 + q) * 2 + 1] = l;
        }
    }
    __syncthreads();
    if (wk == 0) {
        float m1 = mlsc[(wq * 32 + q) * 2 + 0];
        float l1 = mlsc[(wq * 32 + q) * 2 + 1];
        float mm = fmaxf(m, m1);
        float a0 = __expf(m - mm), a1 = __expf(m1 - mm);
        float lL = l * a0 + l1 * a1;

        const size_t pbase = ((size_t)p * 7 + h) * 64;
        const int row = wq * 32 + q;
#pragma unroll
        for (int d4 = 0; d4 < 4; d4++)
#pragma unroll
            for (int rg = 0; rg < 4; rg++) {
                float v0_, v1_, v2_, v3_;
                {
                    int e = rg * 4;
                    int dA = d4 * 32 + 8 * rg + 4 * hl;   // d of (e&3)==0
                    v0_ = O[d4][e + 0] * a0 + sc[((size_t)wq * 128 + dA + 0) * 32 + q] * a1;
                    v1_ = O[d4][e + 1] * a0 + sc[((size_t)wq * 128 + dA + 1) * 32 + q] * a1;
                    v2_ = O[d4][e + 2] * a0 + sc[((size_t)wq * 128 + dA + 2) * 32 + q] * a1;
                    v3_ = O[d4][e + 3] * a0 + sc[((size_t)wq * 128 + dA + 3) * 32 + q] * a1;
                }
                uint2 u;
                u.x = pk_bf2(v0_, v1_);
                u.y = pk_bf2(v2_, v3_);
                *(uint2*)&Opart[(pbase + row) * 128 + d4 * 32 + 8 * rg + 4 * hl] = u;
            }
        if (hl == 0) {
            Lm[(pbase + row) * 2 + 0] = mm;
            Lm[(pbase + row) * 2 + 1] = lL;
        }
    }
}

// ---------------------------------------------------------------------------
// Merge variable-count partials -> Ab (bf16). Grid (64,7), block 256.
// Thread = (local row = t>>2, 32-dim slice = (t&3)*32). Tile tt reads splits
// p in [P[tt], P[tt]+S(tt)), S <= MAXSPLIT; unroll-8 with guards keeps all
// array indexing static (no scratch).
// ---------------------------------------------------------------------------
__global__ __launch_bounds__(256)
void attn_merge(const ushort_t* __restrict__ Opart,
                const float* __restrict__ Lm,
                ushort_t* __restrict__ Ab) {
    const int h = blockIdx.y;
    const int tt = blockIdx.x;
    int pb = 0;
    for (int u = 0; u < tt; ++u) pb += nsplit_of(u);
    const int S = nsplit_of(tt);          // 1..8
    const int lrow = threadIdx.x >> 2;
    const int row = tt * 64 + lrow;
    const int d0 = (threadIdx.x & 3) * 32;

    float ms[MAXSPLIT], ls[MAXSPLIT], M = -1e30f;
#pragma unroll
    for (int s = 0; s < MAXSPLIT; s++) {
        ms[s] = -1e30f;
        ls[s] = 0.f;
        if (s < S) {
            size_t q = (((size_t)(pb + s) * 7 + h) * 64 + lrow) * 2;
            ms[s] = Lm[q];
            ls[s] = Lm[q + 1];
        }
        M = fmaxf(M, ms[s]);
    }
    float L = 0.f, c[MAXSPLIT];
#pragma unroll
    for (int s = 0; s < MAXSPLIT; s++) {
        c[s] = __expf(ms[s] - M);   // s>=S: exp(-1e30-M) == 0
        L += c[s] * ls[s];
    }
    float acc[32];
#pragma unroll
    for (int k = 0; k < 32; k++) acc[k] = 0.f;
#pragma unroll
    for (int s = 0; s < MAXSPLIT; s++) {
        if (s < S) {
            const float cs = c[s];
            const ushort_t* op =
                Opart + (((size_t)(pb + s) * 7 + h) * 64 + lrow) * 128 + d0;
#pragma unroll
            for (int v = 0; v < 4; v++) {
                uint4 u = *(const uint4*)(op + v * 8);
                acc[v * 8 + 0] += cs * lo_f(u.x);
                acc[v * 8 + 1] += cs * hi_f(u.x);
                acc[v * 8 + 2] += cs * lo_f(u.y);
                acc[v * 8 + 3] += cs * hi_f(u.y);
                acc[v * 8 + 4] += cs * lo_f(u.z);
                acc[v * 8 + 5] += cs * hi_f(u.z);
                acc[v * 8 + 6] += cs * lo_f(u.w);
                acc[v * 8 + 7] += cs * hi_f(u.w);
            }
        }
    }
    float invL = 1.f / L;   // L > 0: j==i lies in some split
    ushort_t* dst = Ab + (size_t)row * D_MODEL + h * 128 + d0;
#pragma unroll
    for (int v = 0; v < 4; v++) {
        uint4 u;
        u.x = f2bf(acc[v * 8 + 0] * invL) | (f2bf(acc[v * 8 + 1] * invL) << 16);
        u.y = f2bf(acc[v * 8 + 2] * invL) | (f2bf(acc[v * 8 + 3] * invL) << 16);
        u.z = f2bf(acc[v * 8 + 4] * invL) | (f2bf(acc[v * 8 + 5] * invL) << 16);
        u.w = f2bf(acc[v * 8 + 6] * invL) | (f2bf(acc[v * 8 + 7] * invL) << 16);
        *(uint4*)(dst + v * 8) = u;
    }
}

extern "C" void kernel_launch(void* const* d_in, const int* in_sizes, int n_in,
                              void* d_out, int out_size, void* d_ws, size_t ws_size,
                              hipStream_t stream) {
    const float* x  = (const float*)d_in[0];   // fp32 [4096, 896]
    const float* Wq = (const float*)d_in[1];   // fp32 [896, 896]
    const float* Wk = (const float*)d_in[2];
    const float* Wv = (const float*)d_in[3];
    const float* Wo = (const float*)d_in[4];

    // total attention blocks in the balanced schedule
    int NP = 0;
    for (int u = 0; u < 64; ++u) NP += nsplit_of(u);

    const size_t n  = (size_t)T_SEQ * D_MODEL;
    const size_t nw = (size_t)D_MODEL * D_MODEL;
    ushort_t* xb  = (ushort_t*)d_ws + 128;   // 256B offset
    ushort_t* Wqb = xb + n;
    ushort_t* Wkb = Wqb + nw;
    ushort_t* Wvb = Wkb + nw;
    ushort_t* Wob = Wvb + nw;
    ushort_t* Qb  = Wob + nw;
    ushort_t* Kb  = Qb + n;
    ushort_t* Vb  = Kb + n;
    ushort_t* Ab  = Vb + n;
    ushort_t* Opart = Ab + n;                          // NP*7*64*128 bf16
    float*    Lm  = (float*)(Opart + (size_t)NP * 7 * 64 * 128);

    // 0: fp32 -> bf16 bulk convert (x + 4 weights)
    cvt5<<<dim3(1792, 5), 256, 0, stream>>>(x, Wq, Wk, Wv, Wo,
                                            xb, Wqb, Wkb, Wvb, Wob);
    // 1: Q/K/V = x @ W^T (bf16, DMA-staged)
    gemm_nt_dma<false><<<dim3(32, 7, 3), 256, 0, stream>>>(
        xb, Wqb, Wkb, Wvb, Qb, Kb, Vb);
    // 2: balanced split-K sparse attention -> partials
    fano_attn_split<<<dim3(NP, 7), 256, 0, stream>>>(
        Qb, Kb, Vb, Opart, Lm);
    // 3: merge partials -> Ab
    attn_merge<<<dim3(64, 7), 256, 0, stream>>>(Opart, Lm, Ab);
    // 4: out = Ab @ Wo^T -> fp32
    gemm_nt_dma<true><<<dim3(32, 7, 1), 256, 0, stream>>>(
        Ab, Wob, Wob, Wob, d_out, d_out, d_out);
}